// Round 9
// baseline (147.465 us; speedup 1.0000x reference)
//
#include <hip/hip_runtime.h>
#include <hip/hip_bf16.h>

#define Hh 50

typedef __attribute__((ext_vector_type(8))) short bf16x8;
typedef __attribute__((ext_vector_type(4))) float f32x4;
typedef __attribute__((ext_vector_type(16))) float f32x16;

static __device__ __forceinline__ short b16(float x) {
    return __builtin_bit_cast(short, __float2bfloat16(x));
}
// convert 8 contiguous f32 to a bf16x8 MFMA fragment
static __device__ __forceinline__ bf16x8 cvt8(const float* p) {
    f32x4 a = *(const f32x4*)p;
    f32x4 b = *(const f32x4*)(p + 4);
    bf16x8 r;
    r[0] = b16(a[0]); r[1] = b16(a[1]); r[2] = b16(a[2]); r[3] = b16(a[3]);
    r[4] = b16(b[0]); r[5] = b16(b[1]); r[6] = b16(b[2]); r[7] = b16(b[3]);
    return r;
}

// -------- Kernel 0: pack wh_w into per-fragment bf16 layout (32x32x16 operand) --------
// whpk[((p*16+ks)*64 + l)*8 + j] = bf16(wh_w[col*256 + k]),
//   col = p*32 + (l&31), k = ks*16 + (l>>5)*8 + j.
// Same lane-mapping serves as A-operand (m=l&31) in k_alpha.
__global__ __launch_bounds__(256) void k_prep(const float* __restrict__ w,
                                              short* __restrict__ o) {
    int t = (int)blockIdx.x * 256 + threadIdx.x;   // 0..8191
    int p  = t >> 10;
    int ks = (t >> 6) & 15;
    int l  = t & 63;
    int col = p * 32 + (l & 31);
    int k   = ks * 16 + (l >> 5) * 8;
    bf16x8 v = cvt8(w + (size_t)col * 256 + k);
    *(bf16x8*)(o + (size_t)t * 8) = v;
}

// ---------------- Kernel 1: wcplus[4096][256] (f32) = cur @ wc_w^T + wc_b + wh_b ------
__global__ __launch_bounds__(64) void k_wc(const float* __restrict__ cur,
                                           const float* __restrict__ wcw,
                                           const float* __restrict__ wcb,
                                           const float* __restrict__ whb,
                                           float* __restrict__ out) {
    int l = threadIdx.x;
    int m0 = (int)(blockIdx.x >> 2) * 16;
    int ntb = (int)(blockIdx.x & 3) * 4;
    int lk = (l >> 4) * 8;

    bf16x8 Af[8];
#pragma unroll
    for (int k = 0; k < 8; k++)
        Af[k] = cvt8(cur + (size_t)(m0 + (l & 15)) * 256 + k * 32 + lk);

#pragma unroll
    for (int nt = 0; nt < 4; nt++) {
        int col = (ntb + nt) * 16 + (l & 15);
        f32x4 a = {0.f, 0.f, 0.f, 0.f};
#pragma unroll
        for (int k = 0; k < 8; k++) {
            bf16x8 Bf = cvt8(wcw + (size_t)col * 256 + k * 32 + lk);
            a = __builtin_amdgcn_mfma_f32_16x16x32_bf16(Af[k], Bf, a, 0, 0, 0);
        }
        float bias = wcb[col] + whb[col];
        int row = m0 + (l >> 4) * 4;
#pragma unroll
        for (int r = 0; r < 4; r++)
            out[(size_t)(row + r) * 256 + col] = a[r] + bias;
    }
}

// ---------------- Kernel 2: alpha[b,h,s] = qtb + sum_col qt[col]*sigmoid(wh_out+wcplus) ----
// Block = (b, h, 64 consecutive s). 256 thr = 4 waves; wave w does panels p=w, w+4
// (32 wh-cols each) x 2 nt (32 s each). A = wh_w panel resident in regs (from whpk),
// B = hist from swizzled LDS. Staging is one contiguous 64 KB read. No pad rows.
__global__ __launch_bounds__(256, 4)
void k_alpha(const float* __restrict__ hist,
             const float* __restrict__ wcplus,
             const short* __restrict__ whpk,
             const float* __restrict__ qtw,
             const float* __restrict__ qtb,
             float* __restrict__ alphaWS) {
    __shared__ __align__(16) char histA[64 * 512];   // swizzled bf16 [s][256]
    __shared__ float alphaP[8][64];

    int tid = threadIdx.x;
    int l = tid & 63;
    int w = tid >> 6;
    int x = (int)blockIdx.x;          // ((b*50 + h)*8 + st)
    int b = x / 400;
    int rem = x - b * 400;
    int h = rem >> 3;
    int s0 = (rem & 7) * 64;

    // stage 64 contiguous s-rows (64 KB f32 -> 32 KB bf16, swizzled)
    const float* hsrc = hist + ((size_t)(b * Hh + h) * 512 + s0) * 256;
#pragma unroll
    for (int i = 0; i < 8; i++) {
        int c = tid + i * 256;        // 0..2047
        int r = c >> 5, g = c & 31;
        bf16x8 v = cvt8(hsrc + r * 256 + g * 8);
        *(bf16x8*)(&histA[r * 512 + ((g ^ (r & 15)) << 4)]) = v;
    }
    __syncthreads();

#pragma unroll 1
    for (int pi = 0; pi < 2; pi++) {
        int p = w + pi * 4;
        // A fragments for panel p: 16 x 1KB contiguous wave-loads from L2 (64 VGPR)
        const short* wqp = whpk + ((size_t)(p * 16) * 64 + l) * 8;
        bf16x8 Af[16];
#pragma unroll
        for (int ks = 0; ks < 16; ks++)
            Af[ks] = *(const bf16x8*)(wqp + ks * 512);

#pragma unroll 1
        for (int nt = 0; nt < 2; nt++) {
            int sl = nt * 32 + (l & 31);
            int s = s0 + sl;

            f32x16 acc;
#pragma unroll
            for (int i = 0; i < 16; i++) acc[i] = 0.f;
#pragma unroll
            for (int ks = 0; ks < 16; ks++) {
                int g = ks * 2 + (l >> 5);
                bf16x8 Bf = *(const bf16x8*)(&histA[sl * 512 + ((g ^ (sl & 15)) << 4)]);
                acc = __builtin_amdgcn_mfma_f32_32x32x16_bf16(Af[ks], Bf, acc, 0, 0, 0);
            }

            // epilogue: bias gather (4x dwordx4) + qt gather, sigmoid, reduce
            const float* wbp = wcplus + (size_t)(b * 512 + s) * 256 + p * 32 + 4 * (l >> 5);
            const float* qp = qtw + p * 32 + 4 * (l >> 5);
            float pal = 0.f;
#pragma unroll
            for (int q = 0; q < 4; q++) {
                f32x4 wq = *(const f32x4*)(wbp + 8 * q);
                f32x4 qv = *(const f32x4*)(qp + 8 * q);
#pragma unroll
                for (int j = 0; j < 4; j++) {
                    float v = acc[q * 4 + j] + wq[j];
                    float sg = __builtin_amdgcn_rcpf(1.0f + __expf(-v));
                    pal += qv[j] * sg;
                }
            }
            pal += __shfl_xor(pal, 32);
            if (l < 32) alphaP[p][sl] = pal;
        }
    }
    __syncthreads();

    if (tid < 64) {
        float a = qtb[0];
#pragma unroll
        for (int p = 0; p < 8; p++) a += alphaP[p][tid];
        alphaWS[(size_t)(b * Hh + h) * 512 + s0 + tid] = a;
    }
}

// ---------------- Kernel 3: hsum[b,s,:] = sum_h alpha[b,h,s] * hist[b,h,s,:] ----------
// Block = (b, 4 consecutive s); wave reads one 1 KB row per h, fully coalesced.
__global__ __launch_bounds__(256, 8)
void k_hsum(const float* __restrict__ hist,
            const float* __restrict__ alphaWS,
            float* __restrict__ hsum) {
    int tid = threadIdx.x;
    int x = (int)blockIdx.x;          // b*128 + sc
    int b = x >> 7, sc = x & 127;
    int s = sc * 4 + (tid >> 6);
    int d = (tid & 63) * 4;

    const float* hp = hist + ((size_t)(b * Hh) * 512 + s) * 256 + d;
    const float* ap = alphaWS + (size_t)(b * Hh) * 512 + s;
    f32x4 acc = {0.f, 0.f, 0.f, 0.f};
#pragma unroll 2
    for (int h = 0; h < Hh; h++) {
        f32x4 v = *(const f32x4*)(hp + (size_t)h * 512 * 256);
        float a = ap[(size_t)h * 512];
        acc[0] += a * v[0]; acc[1] += a * v[1];
        acc[2] += a * v[2]; acc[3] += a * v[3];
    }
    *(f32x4*)(hsum + ((size_t)b * 512 + s) * 256 + d) = acc;
}

// ---------------- Kernel 4: out[4096][128] (f32) = [cur, hsum] @ wf_w^T + wf_b --------
__global__ __launch_bounds__(64) void k_wf(const float* __restrict__ cur,
                                           const float* __restrict__ hsum,
                                           const float* __restrict__ wfw,
                                           const float* __restrict__ wfb,
                                           float* __restrict__ out) {
    int l = threadIdx.x;
    int m0 = (int)(blockIdx.x >> 1) * 16;
    int ntb = (int)(blockIdx.x & 1) * 4;
    int lk = (l >> 4) * 8;

    f32x4 acc[4];
#pragma unroll
    for (int nt = 0; nt < 4; nt++) acc[nt] = (f32x4){0.f, 0.f, 0.f, 0.f};

#pragma unroll
    for (int k = 0; k < 16; k++) {
        int row = m0 + (l & 15);
        bf16x8 Af;
        if (k < 8)
            Af = cvt8(cur + (size_t)row * 256 + k * 32 + lk);
        else
            Af = cvt8(hsum + (size_t)row * 256 + (k - 8) * 32 + lk);
#pragma unroll
        for (int nt = 0; nt < 4; nt++) {
            int col = (ntb + nt) * 16 + (l & 15);
            bf16x8 Bf = cvt8(wfw + (size_t)col * 512 + k * 32 + lk);
            acc[nt] = __builtin_amdgcn_mfma_f32_16x16x32_bf16(Af, Bf, acc[nt], 0, 0, 0);
        }
    }
#pragma unroll
    for (int nt = 0; nt < 4; nt++) {
        int col = (ntb + nt) * 16 + (l & 15);
        float bias = wfb[col];
        int row = m0 + (l >> 4) * 4;
#pragma unroll
        for (int r = 0; r < 4; r++)
            out[(size_t)(row + r) * 128 + col] = acc[nt][r] + bias;
    }
}

extern "C" void kernel_launch(void* const* d_in, const int* in_sizes, int n_in,
                              void* d_out, int out_size, void* d_ws, size_t ws_size,
                              hipStream_t stream) {
    const float* hist = (const float*)d_in[0];
    const float* cur  = (const float*)d_in[1];
    const float* wc_w = (const float*)d_in[2];
    const float* wc_b = (const float*)d_in[3];
    const float* wh_w = (const float*)d_in[4];
    const float* wh_b = (const float*)d_in[5];
    const float* qt_w = (const float*)d_in[6];
    const float* qt_b = (const float*)d_in[7];
    const float* wf_w = (const float*)d_in[8];
    const float* wf_b = (const float*)d_in[9];

    float* wc_ws   = (float*)d_ws;                                          // 4 MB
    float* hsum    = (float*)((char*)d_ws + ((size_t)4 << 20));             // 4 MB
    short* whpk    = (short*)((char*)d_ws + ((size_t)8 << 20));             // 128 KB
    float* alphaWS = (float*)((char*)d_ws + ((size_t)8 << 20) + 131072);    // 800 KB

    k_prep<<<32, 256, 0, stream>>>(wh_w, whpk);
    k_wc<<<1024, 64, 0, stream>>>(cur, wc_w, wc_b, wh_b, wc_ws);
    k_alpha<<<3200, 256, 0, stream>>>(hist, wc_ws, whpk, qt_w, qt_b, alphaWS);
    k_hsum<<<1024, 256, 0, stream>>>(hist, alphaWS, hsum);
    k_wf<<<512, 64, 0, stream>>>(cur, hsum, wf_w, wf_b, (float*)d_out);
}